// Round 14
// baseline (29.577 us; speedup 1.0000x reference)
//
#include <hip/hip_runtime.h>
#include <math.h>

#define BB 4
#define TT 2048
#define DIM 256
#define MROWS (BB*TT)               // 8192
#define MN ((size_t)MROWS*DIM)      // 2097152 elements per tensor
#define SCALE 0.0625f
#define HALF 16

typedef __attribute__((ext_vector_type(8))) short short8;
typedef __attribute__((ext_vector_type(4))) float f32x4;
typedef __attribute__((ext_vector_type(8))) unsigned short ushort8v;

__device__ __forceinline__ ushort f2bf(float f) {
    unsigned u = __builtin_bit_cast(unsigned, f);
    u += 0x7fffu + ((u >> 16) & 1u);
    return (ushort)(u >> 16);
}
__device__ __forceinline__ float bf2f(ushort u) {
    return __builtin_bit_cast(float, (unsigned)u << 16);
}
__device__ __forceinline__ unsigned cvtpk(float lo, float hi) {
    unsigned r;
    asm("v_cvt_pk_bf16_f32 %0, %1, %2" : "=v"(r) : "v"(lo), "v"(hi));
    return r;
}
__device__ __forceinline__ ushort8v pack8(f32x4 lo, f32x4 hi) {
    union { unsigned u[4]; ushort8v v; } r;
    r.u[0] = cvtpk(lo[0], lo[1]);
    r.u[1] = cvtpk(lo[2], lo[3]);
    r.u[2] = cvtpk(hi[0], hi[1]);
    r.u[3] = cvtpk(hi[2], hi[3]);
    return r.v;
}

#define GLOAD16(g, l) __builtin_amdgcn_global_load_lds( \
    (const __attribute__((address_space(1))) void*)(g), \
    (__attribute__((address_space(3))) void*)(l), 16, 0, 0)

// ---------------- prep: x->bf16, Wcat->bf16 (one-time conversion) ----------------
__global__ __launch_bounds__(256) void prep_kernel(
    const float* __restrict__ x,
    const float* __restrict__ Wq, const float* __restrict__ Wk, const float* __restrict__ Wv,
    ushort* __restrict__ xbf, ushort* __restrict__ wbf)
{
    int idx = blockIdx.x * 256 + threadIdx.x;      // ushort8-group index
    if (idx < 262144) {                            // x: 2097152 elems / 8
        const float* s = x + (size_t)idx * 8;
        f32x4 lo = *(const f32x4*)s;
        f32x4 hi = *(const f32x4*)(s + 4);
        *(ushort8v*)(xbf + (size_t)idx * 8) = pack8(lo, hi);
    } else {                                       // W: 196608 elems / 8
        int widx = idx - 262144;                   // 0..24575
        int row = widx >> 5, g = widx & 31;        // 32 groups per 256-col row
        const float* W = row < 256 ? Wq : (row < 512 ? Wk : Wv);
        const float* s = W + (size_t)(row & 255) * 256 + g * 8;
        f32x4 lo = *(const f32x4*)s;
        f32x4 hi = *(const f32x4*)(s + 4);
        *(ushort8v*)(wbf + (size_t)widx * 8) = pack8(lo, hi);
    }
}

// part layout: idx = (((which*4+b)*2+sum)*256 + col)*16 + mb_local. Overwrite-only.

// ---------------- MFMA GEMM ----------------
// r12 geometry: BM=128, BN=192, BK=64; grid 256 = 1/CU; 512 threads = 8 waves (2m x 4n),
// wave tile 64x48. Staging via global_load_lds width-16 from bf16 buffers (r5 pairing).
#define A_TILE (128*64)
#define B_TILE (192*64)
__global__ __launch_bounds__(512) void gemm_kernel(
    const ushort* __restrict__ xbf, const ushort* __restrict__ wbf,
    const float* __restrict__ bq, const float* __restrict__ bk, const float* __restrict__ bv,
    ushort* __restrict__ qkv, float* __restrict__ part, float* __restrict__ out)
{
    __shared__ ushort As[2 * A_TILE];   // 32 KB
    __shared__ ushort Bs[2 * B_TILE];   // 48 KB
    __shared__ float sred[2][2][192];   // 3 KB

    int tid = threadIdx.x;
    int lane = tid & 63, w = tid >> 6;      // 8 waves
    int wr = w >> 2, wc = w & 3;            // 2m x 4n

    int orig = blockIdx.x;
    if (orig == 0) {
        out[tid] = 0.f; out[512 + tid] = 0.f;   // attn is a later dispatch: race-free
    }

    // XCD-aware remap: 256 blocks, 8 XCDs, 32/XCD (8 contiguous m-panels + all W).
    int wg = (orig & 7) * 32 + (orig >> 3);
    int mb = wg >> 2, nt = wg & 3;
    int m0 = mb * 128, n0 = nt * 192;

    // staging: wave w fills A rows [w*16,+16) (2 insts), B rows [w*24,+24) (3 insts); 8 rows/inst
    int srow = lane >> 3;                 // 0..7 == row&7 for every staged row
    int sc   = lane & 7;
    int kof  = (sc ^ srow) << 3;          // pre-swizzled source k-offset (ushorts)
    const ushort* aSrc = xbf + (size_t)(m0 + w * 16 + srow) * DIM + kof;
    const ushort* bSrc = wbf + (size_t)(n0 + w * 24 + srow) * DIM + kof;

    auto stage = [&](int buf, int kt) {
        int ko = kt * 64;
        #pragma unroll
        for (int i = 0; i < 2; i++)
            GLOAD16(aSrc + (size_t)i * 8 * DIM + ko, &As[buf * A_TILE + (w * 16 + i * 8) * 64]);
        #pragma unroll
        for (int g = 0; g < 3; g++)
            GLOAD16(bSrc + (size_t)g * 8 * DIM + ko, &Bs[buf * B_TILE + (w * 24 + g * 8) * 64]);
    };

    f32x4 acc[4][3] = {};
    int fr = lane & 15, fp = lane >> 4, swz = lane & 7;

    stage(0, 0);
    __syncthreads();
    int cur = 0;
    #pragma unroll
    for (int kt = 0; kt < 4; kt++) {
        if (kt < 3) stage(cur ^ 1, kt + 1);    // loads in flight during MFMA
        const ushort* a_lds = &As[cur * A_TILE];
        const ushort* b_lds = &Bs[cur * B_TILE];
        #pragma unroll
        for (int ks = 0; ks < 2; ks++) {
            short8 af[4], bf[3];
            #pragma unroll
            for (int i = 0; i < 4; i++) {
                int row = wr * 64 + i * 16 + fr;
                int slot = ks * 4 + fp;
                af[i] = *(const short8*)(&a_lds[row * 64 + ((slot ^ swz) << 3)]);
            }
            #pragma unroll
            for (int j = 0; j < 3; j++) {
                int row = wc * 48 + j * 16 + fr;
                int slot = ks * 4 + fp;
                bf[j] = *(const short8*)(&b_lds[row * 64 + ((slot ^ swz) << 3)]);
            }
            #pragma unroll
            for (int i = 0; i < 4; i++)
                #pragma unroll
                for (int j = 0; j < 3; j++)
                    acc[i][j] = __builtin_amdgcn_mfma_f32_16x16x32_bf16(
                        af[i], bf[j], acc[i][j], 0, 0, 0);
        }
        __syncthreads();                   // drains prefetch vmcnt + MFMA lgkm
        cur ^= 1;
    }

    // epilogue: bias, round, store qkv; column sums -> sred -> non-overlapping partials
    int b_idx = mb >> 4;                   // 16 m-blocks per batch
    int mb_local = mb & 15;
    #pragma unroll
    for (int j = 0; j < 3; j++) {
        int lstart = wc * 48 + j * 16;     // never straddles the 256-col boundary
        int gstart = n0 + lstart;
        int whf = gstart >> 8;
        int hbase = gstart & 255;
        const float* bias = whf == 0 ? bq : (whf == 1 ? bk : bv);
        int h = hbase + fr;
        float bb = bias[h];
        float s1 = 0.f, s2 = 0.f;
        ushort* outbase = qkv + (size_t)whf * MN + h;
        #pragma unroll
        for (int i = 0; i < 4; i++) {
            #pragma unroll
            for (int rr = 0; rr < 4; rr++) {
                int row = m0 + wr * 64 + i * 16 + fp * 4 + rr;
                float y = acc[i][j][rr] + bb;
                ushort ub = f2bf(y);
                outbase[(size_t)row * DIM] = ub;
                float yr = bf2f(ub);
                s1 += yr; s2 += yr * yr;
            }
        }
        s1 += __shfl_xor(s1, 16, 64); s1 += __shfl_xor(s1, 32, 64);
        s2 += __shfl_xor(s2, 16, 64); s2 += __shfl_xor(s2, 32, 64);
        if (fp == 0) { sred[0][wr][lstart + fr] = s1; sred[1][wr][lstart + fr] = s2; }
    }
    __syncthreads();
    if (tid < 192) {
        float p1 = sred[0][0][tid] + sred[0][1][tid];
        float p2 = sred[1][0][tid] + sred[1][1][tid];
        int gcol = n0 + tid;
        int whc = gcol >> 8, h = gcol & 255;
        int wb = whc * 4 + b_idx;
        part[((size_t)(wb * 2 + 0) * 256 + h) * 16 + mb_local] = p1;
        part[((size_t)(wb * 2 + 1) * 256 + h) * 16 + mb_local] = p2;
    }
}

// ---------------- banded attention (FROZEN r12) ----------------
__global__ __launch_bounds__(256) void attn_kernel(const ushort* __restrict__ qkv,
                                                   const float* __restrict__ part,
                                                   float* __restrict__ out)
{
    int orig = blockIdx.x + blockIdx.y * 64;
    int wg = (orig & 7) * 32 + (orig >> 3);
    int tile = wg & 63, b = wg >> 6;
    int t0 = tile * 32;

    const ushort* qg = qkv;
    const ushort* kg = qkv + MN;
    const ushort* vg = qkv + 2 * MN;

    __shared__ ushort Qs[32 * 256];
    __shared__ ushort Ks[64 * 256];
    __shared__ ushort Vs[64 * 256];
    __shared__ float Ps[32][65];
    __shared__ float csp[4][64];
    __shared__ float csum[64];
    __shared__ float qsc[256], qsh[256];

    int tid = threadIdx.x;
    int lane = tid & 63, w = tid >> 6;

    // (1) issue RAW K (pre-swizzled src) + RAW V (linear) direct-to-LDS at start
    {
        int r0 = lane >> 5;
        int sp = lane & 31;
        #pragma unroll
        for (int i = 0; i < 8; i++) {
            int rowbase = (w * 8 + i) * 2;
            int r = rowbase + r0;
            int gt = t0 - HALF + r;
            int gtc = gt < 0 ? 0 : (gt > TT - 1 ? TT - 1 : gt);   // clamped rows get csum==0
            int s = sp ^ (r & 7);
            GLOAD16(kg + (size_t)(b * TT + gtc) * DIM + s * 8, &Ks[rowbase * 256]);
            GLOAD16(vg + (size_t)(b * TT + gtc) * DIM + sp * 8, &Vs[rowbase * 256]);
        }
    }

    // (2) reduce stat partials (fixed order -> deterministic), h = tid
    float sums[3][2];
    #pragma unroll
    for (int wq = 0; wq < 3; wq++) {
        #pragma unroll
        for (int sm = 0; sm < 2; sm++) {
            const float* p = part + ((size_t)((wq * 4 + b) * 2 + sm) * 256 + tid) * 16;
            float a = 0.f;
            #pragma unroll
            for (int m4 = 0; m4 < 4; m4++) {
                f32x4 v = *(const f32x4*)(p + m4 * 4);
                a += (v[0] + v[1]) + (v[2] + v[3]);
            }
            sums[wq][sm] = a;
        }
    }
    float mq = sums[0][0] * (1.f / 2048.f);
    float rq = 1.f / sqrtf(sums[0][1] * (1.f / 2048.f) - mq * mq + 1e-5f);
    float mk = sums[1][0] * (1.f / 2048.f);
    float rk = 1.f / sqrtf(sums[1][1] * (1.f / 2048.f) - mk * mk + 1e-5f);
    float mv = sums[2][0] * (1.f / 2048.f);
    float rv = 1.f / sqrtf(sums[2][1] * (1.f / 2048.f) - mv * mv + 1e-5f);
    float qs = rq * rk;
    qsc[tid] = qs;  qsh[tid] = -mq * qs;
    float vscr = rv, vshr = -mv * rv;
    __syncthreads();

    // (3) stage Q (32x256) scaled; K/V gloads still in flight
    #pragma unroll
    for (int i = 0; i < 4; i++) {
        int idx = tid + i * 256;
        int qr = idx >> 5, sp = idx & 31;
        int h0 = sp * 8;
        ushort8v raw = *(const ushort8v*)(qg + ((size_t)(b * TT + t0 + qr)) * DIM + h0);
        ushort8v o;
        #pragma unroll
        for (int e = 0; e < 8; e++)
            o[e] = f2bf(bf2f(raw[e]) * qsc[h0 + e] + qsh[h0 + e]);
        *(ushort8v*)(&Qs[qr * 256 + ((sp ^ (qr & 7)) << 3)]) = o;
    }
    __syncthreads();   // drains Q ds_writes + K/V gload_lds

    // (4) MFMA scores 32x64
    f32x4 sacc[2] = {};
    int fr = lane & 15, fp = lane >> 4, swz = lane & 7;
    int brow = w * 16 + fr;
    #pragma unroll
    for (int ks = 0; ks < 8; ks++) {
        int slot = ks * 4 + fp;
        short8 bfr = *(const short8*)(&Ks[brow * 256 + ((slot ^ swz) << 3)]);
        #pragma unroll
        for (int rf = 0; rf < 2; rf++) {
            int arow = rf * 16 + fr;
            short8 af = *(const short8*)(&Qs[arow * 256 + ((slot ^ swz) << 3)]);
            sacc[rf] = __builtin_amdgcn_mfma_f32_16x16x32_bf16(af, bfr, sacc[rf], 0, 0, 0);
        }
    }
    #pragma unroll
    for (int rf = 0; rf < 2; rf++)
        #pragma unroll
        for (int rr = 0; rr < 4; rr++)
            Ps[rf * 16 + fp * 4 + rr][w * 16 + fr] = sacc[rf][rr];
    __syncthreads();

    // (5) softmax: thread (r = tid>>3) owns cols c0..c0+7
    int r = tid >> 3, c0 = (tid & 7) * 8;
    float sv[8];
    float mx = -1e30f;
    #pragma unroll
    for (int j = 0; j < 8; j++) {
        int c = c0 + j;
        int gt = t0 - HALF + c;
        bool valid = (c >= r) && (c <= r + 32) && (gt >= 0) && (gt < TT);
        sv[j] = valid ? Ps[r][c] * SCALE : -1e30f;
        mx = fmaxf(mx, sv[j]);
    }
    #pragma unroll
    for (int d = 1; d < 8; d <<= 1) mx = fmaxf(mx, __shfl_xor(mx, d, 64));
    float sum = 0.f;
    #pragma unroll
    for (int j = 0; j < 8; j++) { sv[j] = __expf(sv[j] - mx); sum += sv[j]; }
    #pragma unroll
    for (int d = 1; d < 8; d <<= 1) sum += __shfl_xor(sum, d, 64);
    float inv = 1.0f / sum;
    #pragma unroll
    for (int j = 0; j < 8; j++) Ps[r][c0 + j] = sv[j] * inv;
    __syncthreads();

    // (6) partial column sums of P, then fold to csum
    {
        int c = tid & 63, rq4 = tid >> 6;
        float s = 0.f;
        #pragma unroll
        for (int j = 0; j < 8; j++) s += Ps[rq4 * 8 + j][c];
        csp[rq4][c] = s;
    }
    __syncthreads();
    if (tid < 64) csum[tid] = csp[0][tid] + csp[1][tid] + csp[2][tid] + csp[3][tid];
    __syncthreads();

    // (7) PV from LDS V
    int h = tid;
    float o = 0.f;
    #pragma unroll 8
    for (int c = 0; c < 64; c++)
        o += csum[c] * bf2f(Vs[c * 256 + h]);
    o = vscr * o + 32.f * vshr;
    atomicAdd(&out[(size_t)b * DIM + h], o * (1.0f / TT));
}

extern "C" void kernel_launch(void* const* d_in, const int* in_sizes, int n_in,
                              void* d_out, int out_size, void* d_ws, size_t ws_size,
                              hipStream_t stream) {
    const float* x  = (const float*)d_in[0];
    const float* Wq = (const float*)d_in[1];
    const float* bq = (const float*)d_in[2];
    const float* Wk = (const float*)d_in[3];
    const float* bk = (const float*)d_in[4];
    const float* Wv = (const float*)d_in[5];
    const float* bv = (const float*)d_in[6];
    float* out = (float*)d_out;

    ushort* qkv = (ushort*)d_ws;                  // 3*MN ushorts (12.6 MB)
    ushort* xbf = qkv + 3 * MN;                   // MN ushorts (4.2 MB)
    ushort* wbf = xbf + MN;                       // 196608 ushorts (0.4 MB)
    float* part = (float*)(wbf + 196608);         // 98304 floats, overwrite-only

    prep_kernel<<<1120, 256, 0, stream>>>(x, Wq, Wk, Wv, xbf, wbf);
    gemm_kernel<<<dim3(256), 512, 0, stream>>>(xbf, wbf, bq, bk, bv, qkv, part, out);
    attn_kernel<<<dim3(64, 4), 256, 0, stream>>>(qkv, part, out);
}

// Round 15
// 23.271 us; speedup vs baseline: 1.2710x; 1.2710x over previous
//
#include <hip/hip_runtime.h>
#include <math.h>

#define BB 4
#define TT 2048
#define DIM 256
#define MROWS (BB*TT)               // 8192
#define MN ((size_t)MROWS*DIM)      // 2097152 elements per tensor
#define SCALE 0.0625f
#define HALF 16

typedef __attribute__((ext_vector_type(8))) short short8;
typedef __attribute__((ext_vector_type(4))) float f32x4;
typedef __attribute__((ext_vector_type(8))) unsigned short ushort8v;

__device__ __forceinline__ ushort f2bf(float f) {
    unsigned u = __builtin_bit_cast(unsigned, f);
    u += 0x7fffu + ((u >> 16) & 1u);
    return (ushort)(u >> 16);
}
__device__ __forceinline__ float bf2f(ushort u) {
    return __builtin_bit_cast(float, (unsigned)u << 16);
}
__device__ __forceinline__ unsigned cvtpk(float lo, float hi) {
    unsigned r;
    asm("v_cvt_pk_bf16_f32 %0, %1, %2" : "=v"(r) : "v"(lo), "v"(hi));
    return r;
}
__device__ __forceinline__ ushort8v pack8(f32x4 lo, f32x4 hi) {
    union { unsigned u[4]; ushort8v v; } r;
    r.u[0] = cvtpk(lo[0], lo[1]);
    r.u[1] = cvtpk(lo[2], lo[3]);
    r.u[2] = cvtpk(hi[0], hi[1]);
    r.u[3] = cvtpk(hi[2], hi[3]);
    return r.v;
}

#define GLOAD16(g, l) __builtin_amdgcn_global_load_lds( \
    (const __attribute__((address_space(1))) void*)(g), \
    (__attribute__((address_space(3))) void*)(l), 16, 0, 0)

// light barrier: drain LDS ops only; global loads stay in flight across it (T3/T4)
#define LBAR() do { \
    asm volatile("s_waitcnt lgkmcnt(0)" ::: "memory"); \
    __builtin_amdgcn_s_barrier(); \
    __builtin_amdgcn_sched_barrier(0); \
} while (0)

// part layout: idx = (((which*4+b)*2+sum)*256 + col)*16 + mb_local. Overwrite-only.

// ---------------- MFMA GEMM ----------------
// r12 geometry: BM=128, BN=192, BK=64; grid 256 = 1/CU; 512 threads = 8 waves (2m x 4n),
// wave tile 64x48. NEW: 2-deep register prefetch + vmcnt-spanning light barriers.
#define A_TILE (128*64)
#define B_TILE (192*64)
__global__ __launch_bounds__(512) void gemm_kernel(
    const float* __restrict__ x,
    const float* __restrict__ Wq, const float* __restrict__ Wk, const float* __restrict__ Wv,
    const float* __restrict__ bq, const float* __restrict__ bk, const float* __restrict__ bv,
    ushort* __restrict__ qkv, float* __restrict__ part, float* __restrict__ out)
{
    __shared__ ushort As[2 * A_TILE];   // 32 KB
    __shared__ ushort Bs[2 * B_TILE];   // 48 KB
    __shared__ float sred[2][2][192];   // 3 KB

    int tid = threadIdx.x;
    int lane = tid & 63, w = tid >> 6;      // 8 waves
    int wr = w >> 2, wc = w & 3;            // 2m x 4n

    int orig = blockIdx.x;
    if (orig == 0) {
        out[tid] = 0.f; out[512 + tid] = 0.f;   // attn is a later dispatch: race-free
    }

    // XCD-aware remap: 256 blocks, 8 XCDs, 32/XCD (8 contiguous m-panels + all W).
    int wg = (orig & 7) * 32 + (orig >> 3);
    int mb = wg >> 2, nt = wg & 3;
    int m0 = mb * 128, n0 = nt * 192;

    int srow = lane >> 3;                 // 0..7 == row&7
    int sc   = lane & 7;                  // linear 16B slot
    int kof  = (sc ^ srow) << 3;          // swizzled source k-offset
    const float* aRow = x + (size_t)(m0 + w * 16 + srow) * DIM + kof;
    // B rows: wave w covers global cols [n0+w*24, +24) in 3 groups of 8
    const float* bRowP[3];
    #pragma unroll
    for (int g = 0; g < 3; g++) {
        int grow = n0 + w * 24 + g * 8 + srow;
        int whr = grow >> 8;
        const float* Wr = whr == 0 ? Wq : (whr == 1 ? Wk : Wv);
        bRowP[g] = Wr + (size_t)(grow & 255) * DIM + kof;
    }
    int aBase = (w * 16 + srow) * 64 + sc * 8;
    int bBase = (w * 24 + srow) * 64 + sc * 8;

    f32x4 acc[4][3] = {};
    f32x4 ra[2][2][2], rb[2][3][2];       // [set][group][half]; full-unroll -> static idx

    auto loadT = [&](int s, int kt) {
        int ko = kt * 64;
        #pragma unroll
        for (int g = 0; g < 2; g++) {
            ra[s][g][0] = *(const f32x4*)(aRow + (size_t)g * 8 * DIM + ko);
            ra[s][g][1] = *(const f32x4*)(aRow + (size_t)g * 8 * DIM + ko + 4);
        }
        #pragma unroll
        for (int g = 0; g < 3; g++) {
            rb[s][g][0] = *(const f32x4*)(bRowP[g] + ko);
            rb[s][g][1] = *(const f32x4*)(bRowP[g] + ko + 4);
        }
    };
    auto commitT = [&](int buf, int s) {
        ushort* Ab = &As[buf * A_TILE];
        ushort* Bb = &Bs[buf * B_TILE];
        #pragma unroll
        for (int g = 0; g < 2; g++)
            *(ushort8v*)(&Ab[aBase + g * 8 * 64]) = pack8(ra[s][g][0], ra[s][g][1]);
        #pragma unroll
        for (int g = 0; g < 3; g++)
            *(ushort8v*)(&Bb[bBase + g * 8 * 64]) = pack8(rb[s][g][0], rb[s][g][1]);
    };

    int fr = lane & 15, fp = lane >> 4, swz = lane & 7;

    // prologue: 2 load-sets in flight; commit set0 (auto-waits only set0's vmcnt)
    loadT(0, 0);
    loadT(1, 1);
    commitT(0, 0);
    LBAR();
    #pragma unroll
    for (int kt = 0; kt < 4; kt++) {
        if (kt < 2) loadT(kt & 1, kt + 2);     // overwrite the set committed last iter
        const ushort* a_lds = &As[(kt & 1) * A_TILE];
        const ushort* b_lds = &Bs[(kt & 1) * B_TILE];
        #pragma unroll
        for (int ks = 0; ks < 2; ks++) {
            short8 af[4], bf[3];
            #pragma unroll
            for (int i = 0; i < 4; i++) {
                int row = wr * 64 + i * 16 + fr;
                int slot = ks * 4 + fp;
                af[i] = *(const short8*)(&a_lds[row * 64 + ((slot ^ swz) << 3)]);
            }
            #pragma unroll
            for (int j = 0; j < 3; j++) {
                int row = wc * 48 + j * 16 + fr;
                int slot = ks * 4 + fp;
                bf[j] = *(const short8*)(&b_lds[row * 64 + ((slot ^ swz) << 3)]);
            }
            #pragma unroll
            for (int i = 0; i < 4; i++)
                #pragma unroll
                for (int j = 0; j < 3; j++)
                    acc[i][j] = __builtin_amdgcn_mfma_f32_16x16x32_bf16(
                        af[i], bf[j], acc[i][j], 0, 0, 0);
        }
        if (kt < 3) {
            commitT((kt + 1) & 1, (kt + 1) & 1);   // set loaded a full iter ago
            LBAR();
        }
    }
    __syncthreads();   // full drain before epilogue LDS reuse patterns

    // epilogue: bias, round, store qkv; column sums -> sred -> non-overlapping partials
    int b_idx = mb >> 4;                   // 16 m-blocks per batch
    int mb_local = mb & 15;
    #pragma unroll
    for (int j = 0; j < 3; j++) {
        int lstart = wc * 48 + j * 16;     // never straddles the 256-col boundary
        int gstart = n0 + lstart;
        int whf = gstart >> 8;             // fragment-uniform tensor id
        int hbase = gstart & 255;
        const float* bias = whf == 0 ? bq : (whf == 1 ? bk : bv);
        int h = hbase + fr;
        float bb = bias[h];
        float s1 = 0.f, s2 = 0.f;
        ushort* outbase = qkv + (size_t)whf * MN + h;
        #pragma unroll
        for (int i = 0; i < 4; i++) {
            #pragma unroll
            for (int rr = 0; rr < 4; rr++) {
                int row = m0 + wr * 64 + i * 16 + fp * 4 + rr;
                float y = acc[i][j][rr] + bb;
                ushort ub = f2bf(y);
                outbase[(size_t)row * DIM] = ub;
                float yr = bf2f(ub);
                s1 += yr; s2 += yr * yr;
            }
        }
        s1 += __shfl_xor(s1, 16, 64); s1 += __shfl_xor(s1, 32, 64);
        s2 += __shfl_xor(s2, 16, 64); s2 += __shfl_xor(s2, 32, 64);
        if (fp == 0) { sred[0][wr][lstart + fr] = s1; sred[1][wr][lstart + fr] = s2; }
    }
    __syncthreads();
    if (tid < 192) {
        float p1 = sred[0][0][tid] + sred[0][1][tid];
        float p2 = sred[1][0][tid] + sred[1][1][tid];
        int gcol = n0 + tid;
        int whc = gcol >> 8, h = gcol & 255;
        int wb = whc * 4 + b_idx;
        part[((size_t)(wb * 2 + 0) * 256 + h) * 16 + mb_local] = p1;
        part[((size_t)(wb * 2 + 1) * 256 + h) * 16 + mb_local] = p2;
    }
}

// ---------------- banded attention (FROZEN r12) ----------------
__global__ __launch_bounds__(256) void attn_kernel(const ushort* __restrict__ qkv,
                                                   const float* __restrict__ part,
                                                   float* __restrict__ out)
{
    int orig = blockIdx.x + blockIdx.y * 64;
    int wg = (orig & 7) * 32 + (orig >> 3);
    int tile = wg & 63, b = wg >> 6;
    int t0 = tile * 32;

    const ushort* qg = qkv;
    const ushort* kg = qkv + MN;
    const ushort* vg = qkv + 2 * MN;

    __shared__ ushort Qs[32 * 256];   // q*(rq*rk), bf16, swizzled slots
    __shared__ ushort Ks[64 * 256];   // RAW k, swizzled via pre-swizzled global src
    __shared__ ushort Vs[64 * 256];   // RAW v, linear
    __shared__ float Ps[32][65];
    __shared__ float csp[4][64];
    __shared__ float csum[64];
    __shared__ float qsc[256], qsh[256];

    int tid = threadIdx.x;
    int lane = tid & 63, w = tid >> 6;

    // (1) issue RAW K (pre-swizzled src) + RAW V (linear) direct-to-LDS at start
    {
        int r0 = lane >> 5;
        int sp = lane & 31;
        #pragma unroll
        for (int i = 0; i < 8; i++) {
            int rowbase = (w * 8 + i) * 2;
            int r = rowbase + r0;
            int gt = t0 - HALF + r;
            int gtc = gt < 0 ? 0 : (gt > TT - 1 ? TT - 1 : gt);   // clamped rows get csum==0
            int s = sp ^ (r & 7);
            GLOAD16(kg + (size_t)(b * TT + gtc) * DIM + s * 8, &Ks[rowbase * 256]);
            GLOAD16(vg + (size_t)(b * TT + gtc) * DIM + sp * 8, &Vs[rowbase * 256]);
        }
    }

    // (2) reduce stat partials (fixed order -> deterministic), h = tid
    float sums[3][2];
    #pragma unroll
    for (int wq = 0; wq < 3; wq++) {
        #pragma unroll
        for (int sm = 0; sm < 2; sm++) {
            const float* p = part + ((size_t)((wq * 4 + b) * 2 + sm) * 256 + tid) * 16;
            float a = 0.f;
            #pragma unroll
            for (int m4 = 0; m4 < 4; m4++) {
                f32x4 v = *(const f32x4*)(p + m4 * 4);
                a += (v[0] + v[1]) + (v[2] + v[3]);
            }
            sums[wq][sm] = a;
        }
    }
    float mq = sums[0][0] * (1.f / 2048.f);
    float rq = 1.f / sqrtf(sums[0][1] * (1.f / 2048.f) - mq * mq + 1e-5f);
    float mk = sums[1][0] * (1.f / 2048.f);
    float rk = 1.f / sqrtf(sums[1][1] * (1.f / 2048.f) - mk * mk + 1e-5f);
    float mv = sums[2][0] * (1.f / 2048.f);
    float rv = 1.f / sqrtf(sums[2][1] * (1.f / 2048.f) - mv * mv + 1e-5f);
    float qs = rq * rk;
    qsc[tid] = qs;  qsh[tid] = -mq * qs;
    float vscr = rv, vshr = -mv * rv;
    __syncthreads();

    // (3) stage Q (32x256) scaled; K/V gloads still in flight
    #pragma unroll
    for (int i = 0; i < 4; i++) {
        int idx = tid + i * 256;
        int qr = idx >> 5, sp = idx & 31;
        int h0 = sp * 8;
        ushort8v raw = *(const ushort8v*)(qg + ((size_t)(b * TT + t0 + qr)) * DIM + h0);
        ushort8v o;
        #pragma unroll
        for (int e = 0; e < 8; e++)
            o[e] = f2bf(bf2f(raw[e]) * qsc[h0 + e] + qsh[h0 + e]);
        *(ushort8v*)(&Qs[qr * 256 + ((sp ^ (qr & 7)) << 3)]) = o;
    }
    __syncthreads();   // drains Q ds_writes + K/V gload_lds

    // (4) MFMA scores 32x64
    f32x4 sacc[2] = {};
    int fr = lane & 15, fp = lane >> 4, swz = lane & 7;
    int brow = w * 16 + fr;
    #pragma unroll
    for (int ks = 0; ks < 8; ks++) {
        int slot = ks * 4 + fp;
        short8 bfr = *(const short8*)(&Ks[brow * 256 + ((slot ^ swz) << 3)]);
        #pragma unroll
        for (int rf = 0; rf < 2; rf++) {
            int arow = rf * 16 + fr;
            short8 af = *(const short8*)(&Qs[arow * 256 + ((slot ^ swz) << 3)]);
            sacc[rf] = __builtin_amdgcn_mfma_f32_16x16x32_bf16(af, bfr, sacc[rf], 0, 0, 0);
        }
    }
    #pragma unroll
    for (int rf = 0; rf < 2; rf++)
        #pragma unroll
        for (int rr = 0; rr < 4; rr++)
            Ps[rf * 16 + fp * 4 + rr][w * 16 + fr] = sacc[rf][rr];
    __syncthreads();

    // (5) softmax: thread (r = tid>>3) owns cols c0..c0+7
    int r = tid >> 3, c0 = (tid & 7) * 8;
    float sv[8];
    float mx = -1e30f;
    #pragma unroll
    for (int j = 0; j < 8; j++) {
        int c = c0 + j;
        int gt = t0 - HALF + c;
        bool valid = (c >= r) && (c <= r + 32) && (gt >= 0) && (gt < TT);
        sv[j] = valid ? Ps[r][c] * SCALE : -1e30f;
        mx = fmaxf(mx, sv[j]);
    }
    #pragma unroll
    for (int d = 1; d < 8; d <<= 1) mx = fmaxf(mx, __shfl_xor(mx, d, 64));
    float sum = 0.f;
    #pragma unroll
    for (int j = 0; j < 8; j++) { sv[j] = __expf(sv[j] - mx); sum += sv[j]; }
    #pragma unroll
    for (int d = 1; d < 8; d <<= 1) sum += __shfl_xor(sum, d, 64);
    float inv = 1.0f / sum;
    #pragma unroll
    for (int j = 0; j < 8; j++) Ps[r][c0 + j] = sv[j] * inv;
    __syncthreads();

    // (6) partial column sums of P, then fold to csum
    {
        int c = tid & 63, rq4 = tid >> 6;
        float s = 0.f;
        #pragma unroll
        for (int j = 0; j < 8; j++) s += Ps[rq4 * 8 + j][c];
        csp[rq4][c] = s;
    }
    __syncthreads();
    if (tid < 64) csum[tid] = csp[0][tid] + csp[1][tid] + csp[2][tid] + csp[3][tid];
    __syncthreads();

    // (7) PV from LDS V (latency hidden under phases 2-5)
    int h = tid;
    float o = 0.f;
    #pragma unroll 8
    for (int c = 0; c < 64; c++)
        o += csum[c] * bf2f(Vs[c * 256 + h]);
    o = vscr * o + 32.f * vshr;
    atomicAdd(&out[(size_t)b * DIM + h], o * (1.0f / TT));
}

extern "C" void kernel_launch(void* const* d_in, const int* in_sizes, int n_in,
                              void* d_out, int out_size, void* d_ws, size_t ws_size,
                              hipStream_t stream) {
    const float* x  = (const float*)d_in[0];
    const float* Wq = (const float*)d_in[1];
    const float* bq = (const float*)d_in[2];
    const float* Wk = (const float*)d_in[3];
    const float* bk = (const float*)d_in[4];
    const float* Wv = (const float*)d_in[5];
    const float* bv = (const float*)d_in[6];
    float* out = (float*)d_out;

    ushort* qkv  = (ushort*)d_ws;                 // 3*MN ushorts (12.6 MB)
    float* part  = (float*)(qkv + 3 * MN);        // 98304 floats, overwrite-only

    gemm_kernel<<<dim3(256), 512, 0, stream>>>(x, Wq, Wk, Wv, bq, bk, bv, qkv, part, out);
    attn_kernel<<<dim3(64, 4), 256, 0, stream>>>(qkv, part, out);
}

// Round 16
// 22.498 us; speedup vs baseline: 1.3147x; 1.0344x over previous
//
#include <hip/hip_runtime.h>
#include <math.h>

#define BB 4
#define TT 2048
#define DIM 256
#define MROWS (BB*TT)               // 8192
#define MN ((size_t)MROWS*DIM)      // 2097152 elements per tensor
#define SCALE 0.0625f
#define HALF 16

typedef __attribute__((ext_vector_type(8))) short short8;
typedef __attribute__((ext_vector_type(4))) float f32x4;
typedef __attribute__((ext_vector_type(8))) unsigned short ushort8v;

__device__ __forceinline__ ushort f2bf(float f) {
    unsigned u = __builtin_bit_cast(unsigned, f);
    u += 0x7fffu + ((u >> 16) & 1u);
    return (ushort)(u >> 16);
}
__device__ __forceinline__ float bf2f(ushort u) {
    return __builtin_bit_cast(float, (unsigned)u << 16);
}
__device__ __forceinline__ unsigned cvtpk(float lo, float hi) {
    unsigned r;
    asm("v_cvt_pk_bf16_f32 %0, %1, %2" : "=v"(r) : "v"(lo), "v"(hi));
    return r;
}
__device__ __forceinline__ ushort8v pack8(f32x4 lo, f32x4 hi) {
    union { unsigned u[4]; ushort8v v; } r;
    r.u[0] = cvtpk(lo[0], lo[1]);
    r.u[1] = cvtpk(lo[2], lo[3]);
    r.u[2] = cvtpk(hi[0], hi[1]);
    r.u[3] = cvtpk(hi[2], hi[3]);
    return r.v;
}

#define GLOAD16(g, l) __builtin_amdgcn_global_load_lds( \
    (const __attribute__((address_space(1))) void*)(g), \
    (__attribute__((address_space(3))) void*)(l), 16, 0, 0)

// light barrier: drain LDS ops only; global loads stay in flight across it (T3/T4)
#define LBAR() do { \
    asm volatile("s_waitcnt lgkmcnt(0)" ::: "memory"); \
    __builtin_amdgcn_s_barrier(); \
    __builtin_amdgcn_sched_barrier(0); \
} while (0)

// part layout: idx = (((which*4+b)*2+sum)*256 + col)*16 + mb_local. Overwrite-only.

// ---------------- MFMA GEMM (FROZEN r15) ----------------
#define A_TILE (128*64)
#define B_TILE (192*64)
__global__ __launch_bounds__(512) void gemm_kernel(
    const float* __restrict__ x,
    const float* __restrict__ Wq, const float* __restrict__ Wk, const float* __restrict__ Wv,
    const float* __restrict__ bq, const float* __restrict__ bk, const float* __restrict__ bv,
    ushort* __restrict__ qkv, float* __restrict__ part, float* __restrict__ out)
{
    __shared__ ushort As[2 * A_TILE];   // 32 KB
    __shared__ ushort Bs[2 * B_TILE];   // 48 KB
    __shared__ float sred[2][2][192];   // 3 KB

    int tid = threadIdx.x;
    int lane = tid & 63, w = tid >> 6;      // 8 waves
    int wr = w >> 2, wc = w & 3;            // 2m x 4n

    int orig = blockIdx.x;
    if (orig == 0) {
        out[tid] = 0.f; out[512 + tid] = 0.f;   // attn is a later dispatch: race-free
    }

    // XCD-aware remap: 256 blocks, 8 XCDs, 32/XCD.
    int wg = (orig & 7) * 32 + (orig >> 3);
    int mb = wg >> 2, nt = wg & 3;
    int m0 = mb * 128, n0 = nt * 192;

    int srow = lane >> 3;
    int sc   = lane & 7;
    int kof  = (sc ^ srow) << 3;
    const float* aRow = x + (size_t)(m0 + w * 16 + srow) * DIM + kof;
    const float* bRowP[3];
    #pragma unroll
    for (int g = 0; g < 3; g++) {
        int grow = n0 + w * 24 + g * 8 + srow;
        int whr = grow >> 8;
        const float* Wr = whr == 0 ? Wq : (whr == 1 ? Wk : Wv);
        bRowP[g] = Wr + (size_t)(grow & 255) * DIM + kof;
    }
    int aBase = (w * 16 + srow) * 64 + sc * 8;
    int bBase = (w * 24 + srow) * 64 + sc * 8;

    f32x4 acc[4][3] = {};
    f32x4 ra[2][2][2], rb[2][3][2];

    auto loadT = [&](int s, int kt) {
        int ko = kt * 64;
        #pragma unroll
        for (int g = 0; g < 2; g++) {
            ra[s][g][0] = *(const f32x4*)(aRow + (size_t)g * 8 * DIM + ko);
            ra[s][g][1] = *(const f32x4*)(aRow + (size_t)g * 8 * DIM + ko + 4);
        }
        #pragma unroll
        for (int g = 0; g < 3; g++) {
            rb[s][g][0] = *(const f32x4*)(bRowP[g] + ko);
            rb[s][g][1] = *(const f32x4*)(bRowP[g] + ko + 4);
        }
    };
    auto commitT = [&](int buf, int s) {
        ushort* Ab = &As[buf * A_TILE];
        ushort* Bb = &Bs[buf * B_TILE];
        #pragma unroll
        for (int g = 0; g < 2; g++)
            *(ushort8v*)(&Ab[aBase + g * 8 * 64]) = pack8(ra[s][g][0], ra[s][g][1]);
        #pragma unroll
        for (int g = 0; g < 3; g++)
            *(ushort8v*)(&Bb[bBase + g * 8 * 64]) = pack8(rb[s][g][0], rb[s][g][1]);
    };

    int fr = lane & 15, fp = lane >> 4, swz = lane & 7;

    loadT(0, 0);
    loadT(1, 1);
    commitT(0, 0);
    LBAR();
    #pragma unroll
    for (int kt = 0; kt < 4; kt++) {
        if (kt < 2) loadT(kt & 1, kt + 2);
        const ushort* a_lds = &As[(kt & 1) * A_TILE];
        const ushort* b_lds = &Bs[(kt & 1) * B_TILE];
        #pragma unroll
        for (int ks = 0; ks < 2; ks++) {
            short8 af[4], bf[3];
            #pragma unroll
            for (int i = 0; i < 4; i++) {
                int row = wr * 64 + i * 16 + fr;
                int slot = ks * 4 + fp;
                af[i] = *(const short8*)(&a_lds[row * 64 + ((slot ^ swz) << 3)]);
            }
            #pragma unroll
            for (int j = 0; j < 3; j++) {
                int row = wc * 48 + j * 16 + fr;
                int slot = ks * 4 + fp;
                bf[j] = *(const short8*)(&b_lds[row * 64 + ((slot ^ swz) << 3)]);
            }
            #pragma unroll
            for (int i = 0; i < 4; i++)
                #pragma unroll
                for (int j = 0; j < 3; j++)
                    acc[i][j] = __builtin_amdgcn_mfma_f32_16x16x32_bf16(
                        af[i], bf[j], acc[i][j], 0, 0, 0);
        }
        if (kt < 3) {
            commitT((kt + 1) & 1, (kt + 1) & 1);
            LBAR();
        }
    }
    __syncthreads();

    int b_idx = mb >> 4;
    int mb_local = mb & 15;
    #pragma unroll
    for (int j = 0; j < 3; j++) {
        int lstart = wc * 48 + j * 16;
        int gstart = n0 + lstart;
        int whf = gstart >> 8;
        int hbase = gstart & 255;
        const float* bias = whf == 0 ? bq : (whf == 1 ? bk : bv);
        int h = hbase + fr;
        float bb = bias[h];
        float s1 = 0.f, s2 = 0.f;
        ushort* outbase = qkv + (size_t)whf * MN + h;
        #pragma unroll
        for (int i = 0; i < 4; i++) {
            #pragma unroll
            for (int rr = 0; rr < 4; rr++) {
                int row = m0 + wr * 64 + i * 16 + fp * 4 + rr;
                float y = acc[i][j][rr] + bb;
                ushort ub = f2bf(y);
                outbase[(size_t)row * DIM] = ub;
                float yr = bf2f(ub);
                s1 += yr; s2 += yr * yr;
            }
        }
        s1 += __shfl_xor(s1, 16, 64); s1 += __shfl_xor(s1, 32, 64);
        s2 += __shfl_xor(s2, 16, 64); s2 += __shfl_xor(s2, 32, 64);
        if (fp == 0) { sred[0][wr][lstart + fr] = s1; sred[1][wr][lstart + fr] = s2; }
    }
    __syncthreads();
    if (tid < 192) {
        float p1 = sred[0][0][tid] + sred[0][1][tid];
        float p2 = sred[1][0][tid] + sred[1][1][tid];
        int gcol = n0 + tid;
        int whc = gcol >> 8, h = gcol & 255;
        int wb = whc * 4 + b_idx;
        part[((size_t)(wb * 2 + 0) * 256 + h) * 16 + mb_local] = p1;
        part[((size_t)(wb * 2 + 1) * 256 + h) * 16 + mb_local] = p2;
    }
}

// ---------------- banded attention: 512 threads, every phase split 2x ----------------
__global__ __launch_bounds__(512) void attn_kernel(const ushort* __restrict__ qkv,
                                                   const float* __restrict__ part,
                                                   float* __restrict__ out)
{
    int orig = blockIdx.x + blockIdx.y * 64;
    int wg = (orig & 7) * 32 + (orig >> 3);
    int tile = wg & 63, b = wg >> 6;
    int t0 = tile * 32;

    const ushort* qg = qkv;
    const ushort* kg = qkv + MN;
    const ushort* vg = qkv + 2 * MN;

    __shared__ ushort Qs[32 * 256];   // 16 KB
    __shared__ ushort Ks[64 * 256];   // 32 KB, swizzled via pre-swizzled global src
    __shared__ ushort Vs[64 * 256];   // 32 KB, linear
    __shared__ float Ps[32][65];      // 8.3 KB
    __shared__ float csp[8][64];
    __shared__ float csum[64];
    __shared__ float sums_lds[6][256];  // 6 KB
    __shared__ float qsc[256], qsh[256], vsc[256], vsh[256];
    __shared__ float osum[2][256];

    int tid = threadIdx.x;
    int lane = tid & 63, w = tid >> 6;    // 8 waves

    // (1) issue RAW K (pre-swizzled src) + RAW V (linear) direct-to-LDS.
    // Wave w covers rows [w*8, w*8+8) as 4 pairs; 8 GLOAD16/thread.
    {
        int r0 = lane >> 5;
        int sp = lane & 31;
        #pragma unroll
        for (int i = 0; i < 4; i++) {
            int rowbase = (w * 4 + i) * 2;
            int r = rowbase + r0;
            int gt = t0 - HALF + r;
            int gtc = gt < 0 ? 0 : (gt > TT - 1 ? TT - 1 : gt);   // clamped rows get csum==0
            int s = sp ^ (r & 7);
            GLOAD16(kg + (size_t)(b * TT + gtc) * DIM + s * 8, &Ks[rowbase * 256]);
            GLOAD16(vg + (size_t)(b * TT + gtc) * DIM + sp * 8, &Vs[rowbase * 256]);
        }
    }

    // (2) stat partials: 1536 sums, 3/thread (same fixed per-sum order as before)
    #pragma unroll
    for (int k = 0; k < 3; k++) {
        int idx = tid + k * 512;          // 0..1535
        int ws_ = idx >> 8;               // (wq*2+sm) in 0..5
        int h = idx & 255;
        int wq = ws_ >> 1, sm = ws_ & 1;
        const float* p = part + ((size_t)((wq * 4 + b) * 2 + sm) * 256 + h) * 16;
        float a = 0.f;
        #pragma unroll
        for (int m4 = 0; m4 < 4; m4++) {
            f32x4 v = *(const f32x4*)(p + m4 * 4);
            a += (v[0] + v[1]) + (v[2] + v[3]);
        }
        sums_lds[ws_][h] = a;
    }
    __syncthreads();
    if (tid < 256) {
        int h = tid;
        float mq = sums_lds[0][h] * (1.f / 2048.f);
        float rq = 1.f / sqrtf(sums_lds[1][h] * (1.f / 2048.f) - mq * mq + 1e-5f);
        float mk = sums_lds[2][h] * (1.f / 2048.f);
        float rk = 1.f / sqrtf(sums_lds[3][h] * (1.f / 2048.f) - mk * mk + 1e-5f);
        float mv = sums_lds[4][h] * (1.f / 2048.f);
        float rv = 1.f / sqrtf(sums_lds[5][h] * (1.f / 2048.f) - mv * mv + 1e-5f);
        float qs = rq * rk;
        qsc[h] = qs;  qsh[h] = -mq * qs;
        vsc[h] = rv;  vsh[h] = -mv * rv;
    }
    __syncthreads();

    // (3) stage Q (32x256) scaled; K/V gloads still in flight; 2 slots/thread
    #pragma unroll
    for (int i = 0; i < 2; i++) {
        int idx = tid + i * 512;
        int qr = idx >> 5, sp = idx & 31;
        int h0 = sp * 8;
        ushort8v raw = *(const ushort8v*)(qg + ((size_t)(b * TT + t0 + qr)) * DIM + h0);
        ushort8v o;
        #pragma unroll
        for (int e = 0; e < 8; e++)
            o[e] = f2bf(bf2f(raw[e]) * qsc[h0 + e] + qsh[h0 + e]);
        *(ushort8v*)(&Qs[qr * 256 + ((sp ^ (qr & 7)) << 3)]) = o;
    }
    __syncthreads();   // drains Q ds_writes + K/V gload_lds

    // (4) MFMA scores 32x64: 8 waves x 1 fragment (rf = w>>2, cf = w&3); 8 MFMAs/wave
    {
        f32x4 sacc = {};
        int fr = lane & 15, fp = lane >> 4, swz = lane & 7;
        int brow = (w & 3) * 16 + fr;
        int arow = (w >> 2) * 16 + fr;
        #pragma unroll
        for (int ks = 0; ks < 8; ks++) {
            int slot = ks * 4 + fp;
            short8 bfr = *(const short8*)(&Ks[brow * 256 + ((slot ^ swz) << 3)]);
            short8 af  = *(const short8*)(&Qs[arow * 256 + ((slot ^ swz) << 3)]);
            sacc = __builtin_amdgcn_mfma_f32_16x16x32_bf16(af, bfr, sacc, 0, 0, 0);
        }
        #pragma unroll
        for (int rr = 0; rr < 4; rr++)
            Ps[(w >> 2) * 16 + fp * 4 + rr][(w & 3) * 16 + fr] = sacc[rr];
    }
    __syncthreads();

    // (5) softmax: 16 threads/row x 4 cols (r = tid>>4, c0 = (tid&15)*4)
    {
        int r = tid >> 4, c0 = (tid & 15) * 4;
        float sv[4];
        float mx = -1e30f;
        #pragma unroll
        for (int j = 0; j < 4; j++) {
            int c = c0 + j;
            int gt = t0 - HALF + c;
            bool valid = (c >= r) && (c <= r + 32) && (gt >= 0) && (gt < TT);
            sv[j] = valid ? Ps[r][c] * SCALE : -1e30f;
            mx = fmaxf(mx, sv[j]);
        }
        #pragma unroll
        for (int d = 1; d < 16; d <<= 1) mx = fmaxf(mx, __shfl_xor(mx, d, 64));
        float sum = 0.f;
        #pragma unroll
        for (int j = 0; j < 4; j++) { sv[j] = __expf(sv[j] - mx); sum += sv[j]; }
        #pragma unroll
        for (int d = 1; d < 16; d <<= 1) sum += __shfl_xor(sum, d, 64);
        float inv = 1.0f / sum;
        #pragma unroll
        for (int j = 0; j < 4; j++) Ps[r][c0 + j] = sv[j] * inv;
    }
    __syncthreads();

    // (6) column sums: 8 groups x 4 rows, then fold
    {
        int c = tid & 63, g = tid >> 6;
        float s = 0.f;
        #pragma unroll
        for (int j = 0; j < 4; j++) s += Ps[g * 4 + j][c];
        csp[g][c] = s;
    }
    __syncthreads();
    if (tid < 64)
        csum[tid] = ((csp[0][tid] + csp[1][tid]) + (csp[2][tid] + csp[3][tid]))
                  + ((csp[4][tid] + csp[5][tid]) + (csp[6][tid] + csp[7][tid]));
    __syncthreads();

    // (7) PV: two 32-col halves in parallel, LDS combine, atomic accumulate
    {
        int h = tid & 255, half = tid >> 8;
        float o = 0.f;
        int cbase = half * 32;
        #pragma unroll 8
        for (int c = 0; c < 32; c++)
            o += csum[cbase + c] * bf2f(Vs[(cbase + c) * 256 + h]);
        osum[half][h] = o;
    }
    __syncthreads();
    if (tid < 256) {
        float oo = osum[0][tid] + osum[1][tid];
        oo = vsc[tid] * oo + 32.f * vsh[tid];
        atomicAdd(&out[(size_t)b * DIM + tid], oo * (1.0f / TT));
    }
}

extern "C" void kernel_launch(void* const* d_in, const int* in_sizes, int n_in,
                              void* d_out, int out_size, void* d_ws, size_t ws_size,
                              hipStream_t stream) {
    const float* x  = (const float*)d_in[0];
    const float* Wq = (const float*)d_in[1];
    const float* bq = (const float*)d_in[2];
    const float* Wk = (const float*)d_in[3];
    const float* bk = (const float*)d_in[4];
    const float* Wv = (const float*)d_in[5];
    const float* bv = (const float*)d_in[6];
    float* out = (float*)d_out;

    ushort* qkv  = (ushort*)d_ws;                 // 3*MN ushorts (12.6 MB)
    float* part  = (float*)(qkv + 3 * MN);        // 98304 floats, overwrite-only

    gemm_kernel<<<dim3(256), 512, 0, stream>>>(x, Wq, Wk, Wv, bq, bk, bv, qkv, part, out);
    attn_kernel<<<dim3(64, 4), 512, 0, stream>>>(qkv, part, out);
}